// Round 5
// baseline (149.576 us; speedup 1.0000x reference)
//
#include <hip/hip_runtime.h>
#include <hip/hip_bf16.h>
#include <math.h>

// KAN layer: out = GELU( einsum('bik,ikj->bj', basis, W) + bias ),
//   basis[b,i,k] = x[b,i]^k, B=4096, D=1024, K=5, U=1024.
//
// Round 8: kill the Ap intermediate (r1-r4 bracketing showed its ~44us cost
// is VOLUME-driven, not access-pattern-driven). Workspace now holds
// Xp = fp32 x transposed into MFMA-unit order (16.8 MB, half of Ap);
// the GEMM builds A-fragments in registers: ds_read_b64 x-pair -> powers
// (f32x2 vector mults) -> f2bf pack. x still arrives via global_load_lds
// DMA (2 x 1KB per k-block, uniform 4 loads/wave/iter -> same counted-vmcnt
// discipline; r2's failure was a GLOBAL x-gather in the vmcnt queue, not
// VALU). Numerics identical to r4 (powers from full fp32 x, then bf16).
// Prep: 512-block transpose-copy + 512-block w-pack writing race-free
// fold8 partials (summed in gemm epilogue). GEMM loop structure frozen.

#define B_DIM 4096
#define D_DIM 1024
#define U_DIM 1024
#define NKB 128             // 32-wide k-blocks

typedef unsigned short ushort_t;
typedef __attribute__((ext_vector_type(8))) short bf16x8;   // MFMA A/B frag
typedef __attribute__((ext_vector_type(4))) float f32x4;    // MFMA C/D frag
typedef __attribute__((ext_vector_type(2))) float f32x2;

__device__ __forceinline__ ushort_t f2bf(float f) {
  union { float f; unsigned int u; } v;
  v.f = f;
  unsigned int r = v.u + 0x7FFFu + ((v.u >> 16) & 1u);
  return (ushort_t)(r >> 16);
}

__device__ __forceinline__ void load_lds16(const ushort_t* g, ushort_t* l) {
  __builtin_amdgcn_global_load_lds(
      (const __attribute__((address_space(1))) ushort_t*)g,
      (__attribute__((address_space(3))) ushort_t*)l, 16, 0, 0);
}

__device__ __forceinline__ float gelu_exact(float v) {
  return 0.5f * v * (1.0f + erff(v * 0.70710678118654752f));
}

// Xp unit (per mt 0..63, it 0..127): 512 floats = 2 KB,
//   element (r4, row, i) at index (r4*16+row)*8 + i  = x[mt*64+r4*16+row][it*8+i]
// Bp unit: unchanged packed bf16 (1 KB), lane l holds row l&15, k-octet l>>4.

// ---------------- merged prep: x-transpose (blocks 0..511) + w-pack/fold (512..1023) ----------------
__global__ __launch_bounds__(256) void prep_kernel(
    const float* __restrict__ x, const float* __restrict__ W,
    float* __restrict__ Xp, ushort_t* __restrict__ Bp,
    float* __restrict__ fold8) {
  __shared__ __align__(16) float lsh[64][132];   // 33.8 KB (x tile, pad 132)

  const int bid  = blockIdx.x;
  const int t    = threadIdx.x;
  const int wave = t >> 6;
  const int lane = t & 63;
  const int m    = lane & 15;
  const int ko   = lane >> 4;

  if (bid < 512) {
    // ---- x part: mt = bid>>3 (64 rows), g = bid&7 (128 i-cols = 16 units) ----
    const int mt = bid >> 3;
    const int g  = bid & 7;
    const float* xbase = x + (size_t)mt * 64 * D_DIM + g * 128;
    // coalesced tile load: each instr = 2 rows x 512 B dense
#pragma unroll
    for (int p = 0; p < 8; ++p) {
      const int row = p * 8 + wave * 2 + (lane >> 5);
      const int c4  = lane & 31;
      *(float4*)&lsh[row][c4 * 4] =
          *(const float4*)(xbase + (size_t)row * D_DIM + c4 * 4);
    }
    __syncthreads();
    // transposed unit stores: lane l = LDS row l, writes floats [l*8..+7] of unit
#pragma unroll
    for (int r = 0; r < 4; ++r) {
      const int itl = r * 4 + wave;           // 0..15
      const int it  = g * 16 + itl;
      float* dst = Xp + ((size_t)(mt * NKB + it)) * 512 + lane * 8;
      float f[8];
#pragma unroll
      for (int j = 0; j < 8; ++j) f[j] = lsh[lane][itl * 8 + j];
      *(float4*)(dst)     = *(const float4*)&f[0];
      *(float4*)(dst + 4) = *(const float4*)&f[4];
    }
  } else {
    // ---- w part: wid -> n16 (16 cols), kg (16 kblks). No atomics: partial
    // fold goes to fold8[kg][j], summed in the gemm epilogue. ----
    const int wid = bid - 512;
    const int n16 = wid >> 3;                 // 0..63
    const int kg  = wid & 7;                  // 0..7
    const int j   = n16 * 16 + m;
    float s0 = 0.0f;
#pragma unroll
    for (int kk = 0; kk < 4; ++kk) {
      const int kblk = kg * 16 + kk * 4 + wave;   // covers kg*16..+15
      const int i0   = kblk * 8 + ko * 2;
      ushort_t o[8];
#pragma unroll
      for (int t2 = 0; t2 < 2; ++t2) {
        const int i = i0 + t2;
        s0 += W[(size_t)(i * 5) * U_DIM + j];     // k=0 plane (ones basis)
#pragma unroll
        for (int e = 0; e < 4; ++e)
          o[t2 * 4 + e] = f2bf(W[(size_t)(i * 5 + e + 1) * U_DIM + j]);
      }
      *(uint4*)(Bp + ((size_t)n16 * NKB + kblk) * 512 + lane * 8) =
          *(const uint4*)o;
    }
    // reduce over ko groups, then across waves via LDS; one store per j
    s0 += __shfl_xor(s0, 16, 64);
    s0 += __shfl_xor(s0, 32, 64);
    float* red = &lsh[0][0];
    if (ko == 0) red[wave * 16 + m] = s0;
    __syncthreads();
    if (wave == 0 && ko == 0)
      fold8[(size_t)kg * U_DIM + j] =
          red[m] + red[16 + m] + red[32 + m] + red[48 + m];
  }
}

// ---------------- main GEMM: 64x128 tile, BK=32, 4-buf counted-vmcnt, x4 unroll ----------------
// buffer layout (ushorts): [0..1023] = x unit (fp32, 2 KB), [1024..5119] =
// 8 B-units (bf16, 1 KB each). 10 KB/buffer x 4 = 40 KB. 4 loads/wave/iter
// (2 x-halves duplicated across waves + 2 B units), prefetch distance 3,
// steady wait vmcnt(8) keeps stages it+1, it+2 in flight across the barrier.
__global__ __launch_bounds__(256) void gemm_kernel(
    const float* __restrict__ Xp, const ushort_t* __restrict__ Bp,
    const float* __restrict__ bias, const float* __restrict__ fold8,
    float* __restrict__ C) {
  __shared__ __align__(16) ushort_t lds[4][5120];   // 4 x 10 KB

  const int tid  = threadIdx.x;
  const int wave = tid >> 6;
  const int lane = tid & 63;
  const int wm   = wave >> 1;             // 0..1 : 32-row half
  const int wn   = wave & 1;              // 0..1 : 64-col half

  // XCD swizzle (bijective, 512 = 8 xcd * 64): each XCD owns an 8m x 8n
  // chunk co-resident on its 32 CUs; its Xp slice (2.1 MB) is L2-resident.
  const int lin  = blockIdx.y * 8 + blockIdx.x;
  const int xcd  = lin & 7;
  const int slot = lin >> 3;              // 0..63
  const int mt   = xcd * 8 + (slot & 7);  // 0..63
  const int nt   = slot >> 3;             // 0..7
  const int m16b = mt * 4;
  const int n16b = nt * 8;

  // staging: every wave loads both x-halves (same dest, benign dup) + 2 B units
  const ushort_t* gx  = (const ushort_t*)(Xp + (size_t)mt * NKB * 512) + lane * 8;
  const ushort_t* gb0 = Bp + ((size_t)(n16b + wave) * NKB) * 512 + lane * 8;
  const ushort_t* gb1 = Bp + ((size_t)(n16b + 4 + wave) * NKB) * 512 + lane * 8;
  const int ldx0 = lane * 8;
  const int ldx1 = 512 + lane * 8;
  const int ldb0 = 1024 + wave * 512 + lane * 8;
  const int ldb1 = 1024 + (4 + wave) * 512 + lane * 8;

  f32x4 acc[2][4];
  const f32x4 zero = {0.0f, 0.0f, 0.0f, 0.0f};
#pragma unroll
  for (int mf = 0; mf < 2; ++mf)
#pragma unroll
    for (int nf = 0; nf < 4; ++nf) acc[mf][nf] = zero;

#define WAITBAR(N) \
  asm volatile("s_waitcnt vmcnt(" #N ")\n\ts_barrier" ::: "memory")

// stage k-block at literal unit offset REL from the rolling pointers
#define STAGE_REL(bb, rel)                                              \
  do {                                                                  \
    load_lds16(gx  + (rel) * 1024,       &lds[bb][ldx0]);               \
    load_lds16(gx  + (rel) * 1024 + 512, &lds[bb][ldx1]);               \
    load_lds16(gb0 + (rel) * 512,        &lds[bb][ldb0]);               \
    load_lds16(gb1 + (rel) * 512,        &lds[bb][ldb1]);               \
  } while (0)

// build one A-frag from an x-pair: powers in f32x2 (compiler packs), bf16 pack
#define PACKA(dst, xp)                                                  \
  do {                                                                  \
    const f32x2 p1 = (xp);                                              \
    const f32x2 p2 = p1 * p1;                                           \
    const f32x2 p3 = p2 * p1;                                           \
    const f32x2 p4 = p2 * p2;                                           \
    bf16x8 rr;                                                          \
    rr[0] = (short)f2bf(p1[0]); rr[1] = (short)f2bf(p2[0]);             \
    rr[2] = (short)f2bf(p3[0]); rr[3] = (short)f2bf(p4[0]);             \
    rr[4] = (short)f2bf(p1[1]); rr[5] = (short)f2bf(p2[1]);             \
    rr[6] = (short)f2bf(p3[1]); rr[7] = (short)f2bf(p4[1]);             \
    dst = rr;                                                           \
  } while (0)

#define COMPUTE(bb)                                                     \
  do {                                                                  \
    const float* xu = (const float*)&lds[bb][0];                        \
    f32x2 xp0 = *(const f32x2*)&xu[((wm * 2 + 0) * 16 + (lane & 15)) * 8 + (lane >> 4) * 2]; \
    f32x2 xp1 = *(const f32x2*)&xu[((wm * 2 + 1) * 16 + (lane & 15)) * 8 + (lane >> 4) * 2]; \
    bf16x8 a[2], b[4];                                                  \
    PACKA(a[0], xp0);                                                   \
    PACKA(a[1], xp1);                                                   \
    _Pragma("unroll")                                                   \
    for (int nf = 0; nf < 4; ++nf)                                      \
      b[nf] = *(const bf16x8*)&lds[bb][1024 + (wn * 4 + nf) * 512 + lane * 8]; \
    _Pragma("unroll")                                                   \
    for (int mf = 0; mf < 2; ++mf)                                      \
      _Pragma("unroll")                                                 \
      for (int nf = 0; nf < 4; ++nf)                                    \
        acc[mf][nf] = __builtin_amdgcn_mfma_f32_16x16x32_bf16(          \
            a[mf], b[nf], acc[mf][nf], 0, 0, 0);                        \
  } while (0)

  // prologue: stage k-blocks 0..2 into buffers 0..2 (12 loads in flight)
  STAGE_REL(0, 0);
  STAGE_REL(1, 1);
  STAGE_REL(2, 2);
  gx  += 4 * 1024;                        // rebase: rel 0 == k-block 4
  gb0 += 4 * 512;
  gb1 += 4 * 512;

  // main loop, chunks of 4: it = base..base+3 computes buffers 0..3,
  // stages k-blocks base+3..base+6 into buffers 3,0,1,2.
  for (int base = 0; base < 124; base += 4) {
    WAITBAR(8); STAGE_REL(3, -1); COMPUTE(0);   // stage base+3
    WAITBAR(8); STAGE_REL(0,  0); COMPUTE(1);   // stage base+4
    WAITBAR(8); STAGE_REL(1,  1); COMPUTE(2);   // stage base+5
    WAITBAR(8); STAGE_REL(2,  2); COMPUTE(3);   // stage base+6
    gx  += 4 * 1024;
    gb0 += 4 * 512;
    gb1 += 4 * 512;
  }
  // tail: it = 124..127 (rel 0 == k-block 128)
  WAITBAR(8); STAGE_REL(3, -1); COMPUTE(0);     // stage 127
  WAITBAR(8); COMPUTE(1);
  WAITBAR(4); COMPUTE(2);
  WAITBAR(0); COMPUTE(3);
#undef STAGE_REL
#undef COMPUTE
#undef PACKA
#undef WAITBAR

  // epilogue: C/D map: col = lane&15, row = (lane>>4)*4 + reg
  const int crow0 = m16b * 16 + wm * 32 + (lane >> 4) * 4;
  const int ccol0 = n16b * 16 + wn * 64 + (lane & 15);
#pragma unroll
  for (int nf = 0; nf < 4; ++nf) {
    const int col = ccol0 + nf * 16;
    float bv = bias[col];
#pragma unroll
    for (int kg = 0; kg < 8; ++kg) bv += fold8[(size_t)kg * U_DIM + col];
#pragma unroll
    for (int mf = 0; mf < 2; ++mf) {
#pragma unroll
      for (int r = 0; r < 4; ++r) {
        const int row = crow0 + mf * 16 + r;
        C[(size_t)row * U_DIM + col] = gelu_exact(acc[mf][nf][r] + bv);
      }
    }
  }
}

// ---------------- fallback (ws too small): fp32, no workspace ----------------
__global__ void fallback_kernel(const float* __restrict__ x, const float* __restrict__ W,
                                const float* __restrict__ bias, float* __restrict__ out) {
  int j  = blockIdx.x * 256 + threadIdx.x;
  int b0 = blockIdx.y * 16;
  float acc[16];
#pragma unroll
  for (int t = 0; t < 16; ++t) acc[t] = 0.0f;
  for (int i = 0; i < D_DIM; ++i) {
    const float* wr = W + (size_t)i * 5 * U_DIM + j;
    float w0 = wr[0 * U_DIM], w1 = wr[1 * U_DIM], w2 = wr[2 * U_DIM];
    float w3 = wr[3 * U_DIM], w4 = wr[4 * U_DIM];
#pragma unroll
    for (int t = 0; t < 16; ++t) {
      float xv = x[(size_t)(b0 + t) * D_DIM + i];
      float x2 = xv * xv;
      acc[t] += w0 + xv * w1 + x2 * w2 + x2 * xv * w3 + x2 * x2 * w4;
    }
  }
  float bv = bias[j];
#pragma unroll
  for (int t = 0; t < 16; ++t)
    out[(size_t)(b0 + t) * U_DIM + j] = gelu_exact(acc[t] + bv);
}

extern "C" void kernel_launch(void* const* d_in, const int* in_sizes, int n_in,
                              void* d_out, int out_size, void* d_ws, size_t ws_size,
                              hipStream_t stream) {
  const float* x    = (const float*)d_in[0];   // (4096, 1024)
  const float* W    = (const float*)d_in[1];   // (1024, 5, 1024), row r = i*5+k
  const float* bias = (const float*)d_in[2];   // (1024,)
  float* out = (float*)d_out;                  // (4096, 1024) fp32

  const size_t szX = (size_t)B_DIM * D_DIM * sizeof(float);      // 16.78 MB
  const size_t szB = (size_t)U_DIM * 4096 * sizeof(ushort_t);    //  8.39 MB
  const size_t szF = (size_t)8 * U_DIM * sizeof(float);          //   32 KB

  if (ws_size >= szX + szB + szF) {
    float*    Xp = (float*)d_ws;
    ushort_t* Bp = (ushort_t*)((char*)d_ws + szX);
    float*    f8 = (float*)((char*)d_ws + szX + szB);
    prep_kernel<<<dim3(1024), 256, 0, stream>>>(x, W, Xp, Bp, f8);
    gemm_kernel<<<dim3(U_DIM / 128, B_DIM / 64), 256, 0, stream>>>(Xp, Bp, bias, f8, out);
  } else {
    fallback_kernel<<<dim3(U_DIM / 256, B_DIM / 16), 256, 0, stream>>>(x, W, bias, out);
  }
}

// Round 6
// 132.399 us; speedup vs baseline: 1.1297x; 1.1297x over previous
//
#include <hip/hip_runtime.h>
#include <hip/hip_bf16.h>
#include <math.h>

// KAN layer: out = GELU( einsum('bik,ikj->bj', basis, W) + bias ),
//   basis[b,i,k] = x[b,i]^k, B=4096, D=1024, K=5, U=1024.
//
// Round 9: NO x intermediate at all. The GEMM DMA-stages raw fp32 x rows
// (global_load_lds gather: lane->row, 32 lines/instr, L2-resident per-XCD
// slice) and builds A-fragments in-register. r5's two measured failure
// modes fixed: (a) pack = v_cvt_pk_bf16_f32 inline asm (8 insts vs 64
// integer ops -- r5's +19us VALU), (b) 16B-granule XOR swizzle on the
// per-lane GLOBAL source (chunk ^= (row>>2)&1) halves the x-read bank
// conflict (4-way -> 2-way; r5's 6.3M conflicts). vmcnt discipline is the
// PROVEN r6 loop verbatim: 3 loads/wave/iter, WAITBAR(6), distance 3.
// Prep = w_pack only (512 blocks, race-free fold8 partials summed in the
// GEMM epilogue). Workspace 8.4 MB. Dispatches: 2.

#define B_DIM 4096
#define D_DIM 1024
#define U_DIM 1024
#define NKB 128             // 32-wide k-blocks

typedef unsigned short ushort_t;
typedef __attribute__((ext_vector_type(8))) short bf16x8;   // MFMA A/B frag
typedef __attribute__((ext_vector_type(4))) float f32x4;    // MFMA C/D frag
typedef __attribute__((ext_vector_type(2))) float f32x2;

__device__ __forceinline__ ushort_t f2bf(float f) {
  union { float f; unsigned int u; } v;
  v.f = f;
  unsigned int r = v.u + 0x7FFFu + ((v.u >> 16) & 1u);
  return (ushort_t)(r >> 16);
}

__device__ __forceinline__ void load_lds16(const ushort_t* g, ushort_t* l) {
  __builtin_amdgcn_global_load_lds(
      (const __attribute__((address_space(1))) ushort_t*)g,
      (__attribute__((address_space(3))) ushort_t*)l, 16, 0, 0);
}

__device__ __forceinline__ float gelu_exact(float v) {
  return 0.5f * v * (1.0f + erff(v * 0.70710678118654752f));
}

// ---------------- prep: W -> B_packed (planes 1..4) + fold k=0 partials ----------------
// Bp unit (per n16, kblk): 512 ushorts = 1 KB; lane l holds col l&15,
// k-octet l>>4. fold8[kg][j] = sum over i in kg*128..+127 of W[i,0,j].
__global__ __launch_bounds__(256) void w_pack_kernel(
    const float* __restrict__ W, ushort_t* __restrict__ Bp,
    float* __restrict__ fold8) {
  __shared__ float red[64];
  const int wid  = blockIdx.x;          // 0..511
  const int t    = threadIdx.x;
  const int wave = t >> 6;
  const int lane = t & 63;
  const int m    = lane & 15;
  const int ko   = lane >> 4;
  const int n16  = wid >> 3;            // 0..63
  const int kg   = wid & 7;             // 0..7
  const int j    = n16 * 16 + m;

  float s0 = 0.0f;
#pragma unroll
  for (int kk = 0; kk < 4; ++kk) {
    const int kblk = kg * 16 + kk * 4 + wave;   // covers kg*16..+15
    const int i0   = kblk * 8 + ko * 2;
    ushort_t o[8];
#pragma unroll
    for (int t2 = 0; t2 < 2; ++t2) {
      const int i = i0 + t2;
      s0 += W[(size_t)(i * 5) * U_DIM + j];     // k=0 plane (ones basis)
#pragma unroll
      for (int e = 0; e < 4; ++e)
        o[t2 * 4 + e] = f2bf(W[(size_t)(i * 5 + e + 1) * U_DIM + j]);
    }
    *(uint4*)(Bp + ((size_t)n16 * NKB + kblk) * 512 + lane * 8) =
        *(const uint4*)o;
  }
  // reduce over ko groups, then across waves via LDS; one store per j
  s0 += __shfl_xor(s0, 16, 64);
  s0 += __shfl_xor(s0, 32, 64);
  if (ko == 0) red[wave * 16 + m] = s0;
  __syncthreads();
  if (wave == 0 && ko == 0)
    fold8[(size_t)kg * U_DIM + j] =
        red[m] + red[16 + m] + red[32 + m] + red[48 + m];
}

// ---------------- main GEMM: 64x128 tile, BK=32, 4-buf counted-vmcnt, x4 unroll ----------------
// Buffer (ushorts): [0..1023] = x fp32 (64 rows x 32 B; 16B chunk t of row r
// holds global i-quad t ^ ((r>>2)&1) -- the XOR swizzle), [1024..5119] =
// 8 Bp units. 10 KB x 4 = 40 KB. Per wave per k-block: 1 x-gather (wave
// pairs duplicate halves: w&1 selects rows 0-31 / 32-63) + 2 B loads = 3,
// identical counts to the proven r6 pipeline (WAITBAR(6), distance 3).
__global__ __launch_bounds__(256) void gemm_kernel(
    const float* __restrict__ x, const ushort_t* __restrict__ Bp,
    const float* __restrict__ bias, const float* __restrict__ fold8,
    float* __restrict__ C) {
  __shared__ __align__(16) ushort_t lds[4][5120];   // 4 x 10 KB

  const int tid  = threadIdx.x;
  const int wave = tid >> 6;
  const int lane = tid & 63;
  const int wm   = wave >> 1;             // 0..1 : 32-row half
  const int wn   = wave & 1;              // 0..1 : 64-col half
  const int m    = lane & 15;
  const int ko   = lane >> 4;

  // XCD swizzle (bijective, 512 = 8 xcd * 64): each XCD owns an 8m x 8n
  // chunk co-resident on its 32 CUs; its x slice (2 MB) is L2-resident.
  const int lin  = blockIdx.y * 8 + blockIdx.x;
  const int xcd  = lin & 7;
  const int slot = lin >> 3;              // 0..63
  const int mt   = xcd * 8 + (slot & 7);  // 0..63
  const int nt   = slot >> 3;             // 0..7
  const int m16b = mt * 4;
  const int n16b = nt * 8;

  // x gather: lane l -> block-local row r = (w&1)*32 + (l>>1), 16B chunk
  // c = l&1, source chunk pre-swizzled: c ^ ((r>>2)&1) = c ^ ((l>>3)&1).
  const int xrow  = (wave & 1) * 32 + (lane >> 1);
  const int xchk  = (lane & 1) ^ ((lane >> 3) & 1);
  const ushort_t* gx =
      (const ushort_t*)(x + ((size_t)(m16b * 16 + xrow)) * D_DIM + xchk * 4);
  const int ldx = (wave & 1) * 512 + lane * 8;      // ushort idx (16B/lane)

  // B staging: wave w stages units w and 4+w (dense 1 KB bursts)
  const ushort_t* gb0 = Bp + ((size_t)(n16b + wave) * NKB) * 512 + lane * 8;
  const ushort_t* gb1 = Bp + ((size_t)(n16b + 4 + wave) * NKB) * 512 + lane * 8;
  const int ldb0 = 1024 + wave * 512 + lane * 8;
  const int ldb1 = 1024 + (4 + wave) * 512 + lane * 8;

  // x read (lane-const byte offset): row = wm*32 + mf*16 + m, wants global
  // i-pair ko -> chunk (ko>>1)^((m>>2)&1), pair (ko&1). mf adds 512 B.
  const int xoff = wm * 1024 + m * 32 +
                   ((((ko >> 1) ^ ((m >> 2) & 1))) << 4) + (ko & 1) * 8;

  f32x4 acc[2][4];
  const f32x4 zero = {0.0f, 0.0f, 0.0f, 0.0f};
#pragma unroll
  for (int mf = 0; mf < 2; ++mf)
#pragma unroll
    for (int nf = 0; nf < 4; ++nf) acc[mf][nf] = zero;

#define WAITBAR(N) \
  asm volatile("s_waitcnt vmcnt(" #N ")\n\ts_barrier" ::: "memory")

// stage k-block at literal unit offset REL from the rolling pointers
#define STAGE_REL(bb, rel)                                              \
  do {                                                                  \
    load_lds16(gx  + (rel) * 16,  &lds[bb][ldx]);                       \
    load_lds16(gb0 + (rel) * 512, &lds[bb][ldb0]);                      \
    load_lds16(gb1 + (rel) * 512, &lds[bb][ldb1]);                      \
  } while (0)

// powers + pack: v_cvt_pk_bf16_f32 (RNE, same rounding as f2bf)
#define PACKA(dst, xp)                                                  \
  do {                                                                  \
    const f32x2 p1 = (xp);                                              \
    const f32x2 p2 = p1 * p1;                                           \
    const f32x2 p3 = p2 * p1;                                           \
    const f32x2 p4 = p2 * p2;                                           \
    union { bf16x8 v; unsigned int u[4]; } r_;                          \
    asm("v_cvt_pk_bf16_f32 %0, %1, %2" : "=v"(r_.u[0]) : "v"(p1[0]), "v"(p2[0])); \
    asm("v_cvt_pk_bf16_f32 %0, %1, %2" : "=v"(r_.u[1]) : "v"(p3[0]), "v"(p4[0])); \
    asm("v_cvt_pk_bf16_f32 %0, %1, %2" : "=v"(r_.u[2]) : "v"(p1[1]), "v"(p2[1])); \
    asm("v_cvt_pk_bf16_f32 %0, %1, %2" : "=v"(r_.u[3]) : "v"(p3[1]), "v"(p4[1])); \
    dst = r_.v;                                                         \
  } while (0)

#define COMPUTE(bb)                                                     \
  do {                                                                  \
    const char* xu = (const char*)&lds[bb][0];                          \
    const f32x2 q0 = *(const f32x2*)(xu + xoff);                        \
    const f32x2 q1 = *(const f32x2*)(xu + xoff + 512);                  \
    bf16x8 a[2], b[4];                                                  \
    PACKA(a[0], q0);                                                    \
    PACKA(a[1], q1);                                                    \
    _Pragma("unroll")                                                   \
    for (int nf = 0; nf < 4; ++nf)                                      \
      b[nf] = *(const bf16x8*)&lds[bb][1024 + (wn * 4 + nf) * 512 + lane * 8]; \
    _Pragma("unroll")                                                   \
    for (int mf = 0; mf < 2; ++mf)                                      \
      _Pragma("unroll")                                                 \
      for (int nf = 0; nf < 4; ++nf)                                    \
        acc[mf][nf] = __builtin_amdgcn_mfma_f32_16x16x32_bf16(          \
            a[mf], b[nf], acc[mf][nf], 0, 0, 0);                        \
  } while (0)

  // prologue: stage k-blocks 0..2 into buffers 0..2 (9 loads in flight)
  STAGE_REL(0, 0);
  STAGE_REL(1, 1);
  STAGE_REL(2, 2);
  gx  += 4 * 16;                          // rebase: rel 0 == k-block 4
  gb0 += 4 * 512;
  gb1 += 4 * 512;

  // main loop, chunks of 4: it = base..base+3 computes buffers 0..3,
  // stages k-blocks base+3..base+6 into buffers 3,0,1,2.
  for (int base = 0; base < 124; base += 4) {
    WAITBAR(6); STAGE_REL(3, -1); COMPUTE(0);   // stage base+3
    WAITBAR(6); STAGE_REL(0,  0); COMPUTE(1);   // stage base+4
    WAITBAR(6); STAGE_REL(1,  1); COMPUTE(2);   // stage base+5
    WAITBAR(6); STAGE_REL(2,  2); COMPUTE(3);   // stage base+6
    gx  += 4 * 16;
    gb0 += 4 * 512;
    gb1 += 4 * 512;
  }
  // tail: it = 124..127 (rel 0 == k-block 128)
  WAITBAR(6); STAGE_REL(3, -1); COMPUTE(0);     // stage 127
  WAITBAR(6); COMPUTE(1);
  WAITBAR(3); COMPUTE(2);
  WAITBAR(0); COMPUTE(3);
#undef STAGE_REL
#undef COMPUTE
#undef PACKA
#undef WAITBAR

  // epilogue: C/D map: col = lane&15, row = (lane>>4)*4 + reg
  const int crow0 = m16b * 16 + wm * 32 + (lane >> 4) * 4;
  const int ccol0 = n16b * 16 + wn * 64 + (lane & 15);
#pragma unroll
  for (int nf = 0; nf < 4; ++nf) {
    const int col = ccol0 + nf * 16;
    float bv = bias[col];
#pragma unroll
    for (int kg = 0; kg < 8; ++kg) bv += fold8[(size_t)kg * U_DIM + col];
#pragma unroll
    for (int mf = 0; mf < 2; ++mf) {
#pragma unroll
      for (int r = 0; r < 4; ++r) {
        const int row = crow0 + mf * 16 + r;
        C[(size_t)row * U_DIM + col] = gelu_exact(acc[mf][nf][r] + bv);
      }
    }
  }
}

// ---------------- fallback (ws too small): fp32, no workspace ----------------
__global__ void fallback_kernel(const float* __restrict__ x, const float* __restrict__ W,
                                const float* __restrict__ bias, float* __restrict__ out) {
  int j  = blockIdx.x * 256 + threadIdx.x;
  int b0 = blockIdx.y * 16;
  float acc[16];
#pragma unroll
  for (int t = 0; t < 16; ++t) acc[t] = 0.0f;
  for (int i = 0; i < D_DIM; ++i) {
    const float* wr = W + (size_t)i * 5 * U_DIM + j;
    float w0 = wr[0 * U_DIM], w1 = wr[1 * U_DIM], w2 = wr[2 * U_DIM];
    float w3 = wr[3 * U_DIM], w4 = wr[4 * U_DIM];
#pragma unroll
    for (int t = 0; t < 16; ++t) {
      float xv = x[(size_t)(b0 + t) * D_DIM + i];
      float x2 = xv * xv;
      acc[t] += w0 + xv * w1 + x2 * w2 + x2 * xv * w3 + x2 * x2 * w4;
    }
  }
  float bv = bias[j];
#pragma unroll
  for (int t = 0; t < 16; ++t)
    out[(size_t)(b0 + t) * U_DIM + j] = gelu_exact(acc[t] + bv);
}

extern "C" void kernel_launch(void* const* d_in, const int* in_sizes, int n_in,
                              void* d_out, int out_size, void* d_ws, size_t ws_size,
                              hipStream_t stream) {
  const float* x    = (const float*)d_in[0];   // (4096, 1024)
  const float* W    = (const float*)d_in[1];   // (1024, 5, 1024), row r = i*5+k
  const float* bias = (const float*)d_in[2];   // (1024,)
  float* out = (float*)d_out;                  // (4096, 1024) fp32

  const size_t szB = (size_t)U_DIM * 4096 * sizeof(ushort_t);    // 8.39 MB
  const size_t szF = (size_t)8 * U_DIM * sizeof(float);          //   32 KB

  if (ws_size >= szB + szF) {
    ushort_t* Bp = (ushort_t*)d_ws;
    float*    f8 = (float*)((char*)d_ws + szB);
    w_pack_kernel<<<dim3(512), 256, 0, stream>>>(W, Bp, f8);
    gemm_kernel<<<dim3(U_DIM / 128, B_DIM / 64), 256, 0, stream>>>(x, Bp, bias, f8, out);
  } else {
    fallback_kernel<<<dim3(U_DIM / 256, B_DIM / 16), 256, 0, stream>>>(x, W, bias, out);
  }
}